// Round 2
// baseline (4985.917 us; speedup 1.0000x reference)
//
#include <hip/hip_runtime.h>
#include <hip/hip_bf16.h>

typedef float f32x4 __attribute__((ext_vector_type(4)));
typedef __bf16 bf16x8 __attribute__((ext_vector_type(8)));
typedef unsigned short u16x8 __attribute__((ext_vector_type(8)));
typedef unsigned short u16;

__device__ __forceinline__ u16 f2bf(float f) {
  unsigned int u = __float_as_uint(f);
  u += 0x7FFFu + ((u >> 16) & 1u);          // RNE
  return (u16)(u >> 16);
}
__device__ __forceinline__ float bf2f(u16 s) {
  return __uint_as_float(((unsigned int)s) << 16);
}
__device__ __forceinline__ float gelu_f(float x) {
  return 0.5f * x * (1.0f + erff(x * 0.70710678118654752f)); // erf GELU
}
__device__ __forceinline__ void gload_lds16(const void* g, void* l) {
  __builtin_amdgcn_global_load_lds((const __attribute__((address_space(1))) void*)g,
                                   (__attribute__((address_space(3))) void*)l, 16, 0, 0);
}

// ---------------- merged weight conversion ----------------
// dst layout (contiguous u16): wE1(524288) wE2(262144) wE3(262144) wD1(262144)
//                              wD2(262144) wD3(524288) wMix(1048576)
__global__ void cvt_all(const float* __restrict__ e1, const float* __restrict__ e2,
                        const float* __restrict__ e3, const float* __restrict__ d1,
                        const float* __restrict__ d2, const float* __restrict__ d3,
                        const float* __restrict__ mx, u16* __restrict__ dst)
{
  int i = blockIdx.x * blockDim.x + threadIdx.x;
  int stride = gridDim.x * blockDim.x;
  for (; i < 3145728; i += stride) {
    float v;
    if (i < 524288)        v = e1[i];
    else if (i < 786432)   v = e2[i - 524288];
    else if (i < 1048576)  v = e3[i - 786432];
    else if (i < 1310720)  v = d1[i - 1048576];
    else if (i < 1572864)  v = d2[i - 1310720];
    else if (i < 2097152)  v = d3[i - 1572864];
    else {
      // mix_w [L,16,16,32,32] (l,bi,j,e,d) -> W[l][o=bi*32+e][k=j*32+d]
      int j = i - 2097152;
      int l = j >> 18, rem = j & 262143;
      int o = rem >> 9, k = rem & 511;
      int bi = o >> 5, e = o & 31, jj = k >> 5, dd = k & 31;
      v = mx[(((l * 16 + bi) * 16 + jj) * 32 + e) * 32 + dd];
    }
    dst[i] = f2bf(v);
  }
}

// ---------------- GEMM: C = A * W^T (+epilogue) ----------------
// EPI: 0 = bias+GELU -> bf16 ; 1 = bias -> bf16 ; 2 = latent combine -> bf16 ; 3 = bias -> f32
// BM=256, BN=128, BK=64, 512 threads (8 waves as 4x2), 1-D grid with XCD swizzle.
template<int EPI, bool AF32>
__global__ __launch_bounds__(512, 6)
void gemm_bt(const void* __restrict__ Ap, const u16* __restrict__ Bw,
             const float* __restrict__ bias, void* __restrict__ Cp,
             const u16* __restrict__ zOld, const float* __restrict__ scales,
             const float* __restrict__ gateBias, int M, int N, int K)
{
  constexpr int BK = 64;
  __shared__ u16 At[256 * BK];
  __shared__ u16 Bt[128 * BK];
  const int tid = threadIdx.x;
  const int lane = tid & 63;
  const int wid = tid >> 6;

  // XCD-aware bijective swizzle: XCD c = bid&7 handles contiguous panel range;
  // the nx blocks sharing an A-panel are adjacent within the XCD's sequence.
  const int nx = N >> 7;               // N-tiles (BN=128)
  const int ny = M >> 8;               // M-panels (BM=256), ny % 8 == 0
  const int d = blockIdx.x;
  const int xcd = d & 7;
  const int i = d >> 3;                // per-XCD sequence index
  const int by = xcd * (ny >> 3) + i / nx;
  const int bx = i - (i / nx) * nx;
  const int m0 = by << 8;
  const int n0 = bx << 7;

  const int wr = wid >> 1, wc = wid & 1;   // 4x2 wave grid, wave tile 64x64
  const int r16 = lane & 15;
  const int kg = (lane >> 4) << 3;         // k sub-offset 0,8,16,24
  const int sw = (r16 & 7) << 4;           // XOR swizzle for ds_read rows

  f32x4 acc[4][4] = {};

  for (int kt = 0; kt < K; kt += BK) {
    // ---- stage A tile [256 x 64] bf16, XOR-swizzled ----
    if constexpr (AF32) {
      const float* Af = (const float*)Ap;
      #pragma unroll
      for (int it = 0; it < 4; ++it) {
        int c = it * 512 + tid;            // 16B-dst chunk id, 2048 chunks
        int row = c >> 3;
        int cb = (c & 7) << 4;
        const float* src = Af + (size_t)(m0 + row) * K + kt + ((c & 7) << 3);
        float4 v0 = *(const float4*)src;
        float4 v1 = *(const float4*)(src + 4);
        u16x8 u;
        u[0] = f2bf(v0.x); u[1] = f2bf(v0.y); u[2] = f2bf(v0.z); u[3] = f2bf(v0.w);
        u[4] = f2bf(v1.x); u[5] = f2bf(v1.y); u[6] = f2bf(v1.z); u[7] = f2bf(v1.w);
        *(u16x8*)((char*)At + row * 128 + (cb ^ ((row & 7) << 4))) = u;
      }
    } else {
      const u16* Ab = (const u16*)Ap;
      #pragma unroll
      for (int it = 0; it < 4; ++it) {
        int c = ((it * 8 + wid) << 6) + lane;       // 2048 chunks
        int row = c >> 3;
        int cb = (c & 7) << 4;
        // rule 21: linear LDS dest + inverse-swizzled global source
        const char* g = (const char*)(Ab + (size_t)(m0 + row) * K + kt) + (cb ^ ((row & 7) << 4));
        char* l = (char*)At + ((it * 8 + wid) << 10);   // wave-uniform base
        gload_lds16(g, l);
      }
    }
    // ---- stage B tile [128 x 64] (weights) ----
    #pragma unroll
    for (int it = 0; it < 2; ++it) {
      int c = ((it * 8 + wid) << 6) + lane;         // 1024 chunks
      int row = c >> 3;
      int cb = (c & 7) << 4;
      const char* g = (const char*)(Bw + (size_t)(n0 + row) * K + kt) + (cb ^ ((row & 7) << 4));
      char* l = (char*)Bt + ((it * 8 + wid) << 10);
      gload_lds16(g, l);
    }
    __syncthreads();

    #pragma unroll
    for (int kk = 0; kk < BK; kk += 32) {
      bf16x8 av[4], bv[4];
      #pragma unroll
      for (int m = 0; m < 4; ++m) {
        int row = wr * 64 + m * 16 + r16;
        av[m] = *(const bf16x8*)((const char*)At + row * 128 + ((((kk + kg) << 1)) ^ sw));
      }
      #pragma unroll
      for (int n = 0; n < 4; ++n) {
        int row = wc * 64 + n * 16 + r16;
        bv[n] = *(const bf16x8*)((const char*)Bt + row * 128 + ((((kk + kg) << 1)) ^ sw));
      }
      #pragma unroll
      for (int m = 0; m < 4; ++m)
        #pragma unroll
        for (int n = 0; n < 4; ++n)
          acc[m][n] = __builtin_amdgcn_mfma_f32_16x16x32_bf16(av[m], bv[n], acc[m][n], 0, 0, 0);
    }
    __syncthreads();
  }

  // ---- epilogue ----  D layout: col = lane&15, row = (lane>>4)*4 + reg
  const int colBase = n0 + wc * 64 + r16;
  const int rowBase = m0 + wr * 64 + ((lane >> 4) << 2);
  #pragma unroll
  for (int n = 0; n < 4; ++n) {
    int col = colBase + n * 16;
    float bv_ = 0.f, gate = 0.f;
    if constexpr (EPI == 0 || EPI == 1 || EPI == 3) bv_ = bias[col];
    if constexpr (EPI == 2) gate = 1.f / (1.f + expf(-gateBias[col >> 5]));
    #pragma unroll
    for (int m = 0; m < 4; ++m) {
      #pragma unroll
      for (int r = 0; r < 4; ++r) {
        int row = rowBase + m * 16 + r;
        float v = acc[m][n][r];
        if constexpr (EPI == 0) {
          ((u16*)Cp)[(size_t)row * N + col] = f2bf(gelu_f(v + bv_));
        } else if constexpr (EPI == 1) {
          ((u16*)Cp)[(size_t)row * N + col] = f2bf(v + bv_);
        } else if constexpr (EPI == 2) {
          float sc = scales[(size_t)row * 16 + (col >> 5)];
          float zo = bf2f(zOld[(size_t)row * 512 + col]);
          ((u16*)Cp)[(size_t)row * N + col] = f2bf(zo * (1.f + sc) + gate * v);
        } else {
          ((float*)Cp)[(size_t)row * N + col] = v + bv_;
        }
      }
    }
  }
}

// ---------------- per-row bundle-norm MLP -> scales ----------------
__global__ __launch_bounds__(256)
void norm_mlp(const u16* __restrict__ z,
              const float* __restrict__ w1, const float* __restrict__ b1,
              const float* __restrict__ w2, const float* __restrict__ b2,
              const float* __restrict__ w3, float* __restrict__ scales, int Mrows)
{
  const int lane = threadIdx.x & 63;
  const int wv = threadIdx.x >> 6;
  for (int row = blockIdx.x * 4 + wv; row < Mrows; row += gridDim.x * 4) {
    u16x8 zv = *(const u16x8*)(z + (size_t)row * 512 + lane * 8);
    float ss = 0.f;
    #pragma unroll
    for (int j = 0; j < 8; ++j) { float f = bf2f(zv[j]); ss += f * f; }
    ss += __shfl_xor(ss, 1);
    ss += __shfl_xor(ss, 2);                 // 4-lane group = one 32-elem bundle
    float nrm = sqrtf(ss) + 1e-8f;
    float h1 = b1[lane];
    #pragma unroll
    for (int i = 0; i < 16; ++i) h1 += __shfl(nrm, i * 4) * w1[lane * 16 + i];
    h1 = gelu_f(h1);
    float h2 = b2[lane];
    #pragma unroll
    for (int k = 0; k < 64; ++k) h2 += __shfl(h1, k) * w2[lane * 64 + k];
    h2 = gelu_f(h2);
    float s = 0.f;
    const int i16 = lane & 15;
    #pragma unroll
    for (int k = 0; k < 64; ++k) s += __shfl(h2, k) * w3[i16 * 64 + k];
    if (lane < 16) {
      s = (s > 20.f) ? s : log1pf(expf(s));  // softplus
      scales[(size_t)row * 16 + lane] = s;
    }
  }
}

// ---------------- launch ----------------
extern "C" void kernel_launch(void* const* d_in, const int* in_sizes, int n_in,
                              void* d_out, int out_size, void* d_ws, size_t ws_size,
                              hipStream_t stream)
{
  (void)in_sizes; (void)n_in; (void)out_size; (void)ws_size;
  const float* x      = (const float*)d_in[0];
  const float* enc_w1 = (const float*)d_in[1];
  const float* enc_b1 = (const float*)d_in[2];
  const float* enc_w2 = (const float*)d_in[3];
  const float* enc_b2 = (const float*)d_in[4];
  const float* enc_w3 = (const float*)d_in[5];
  const float* enc_b3 = (const float*)d_in[6];
  const float* mlp1_w = (const float*)d_in[7];
  const float* mlp1_b = (const float*)d_in[8];
  const float* mlp2_w = (const float*)d_in[9];
  const float* mlp2_b = (const float*)d_in[10];
  const float* mlp3_w = (const float*)d_in[11];
  const float* mix_w  = (const float*)d_in[12];
  const float* gate_b = (const float*)d_in[13];
  const float* dec_w1 = (const float*)d_in[14];
  const float* dec_b1 = (const float*)d_in[15];
  const float* dec_w2 = (const float*)d_in[16];
  const float* dec_b2 = (const float*)d_in[17];
  const float* dec_w3 = (const float*)d_in[18];
  const float* dec_b3 = (const float*)d_in[19];

  char* ws = (char*)d_ws;
  u16*   zA     = (u16*)ws;                            // 64 MB
  u16*   zB     = (u16*)(ws + (size_t)(64u << 20));    // 64 MB
  float* scales = (float*)(ws + (size_t)(128u << 20)); // 4 MB
  u16*   wBase  = (u16*)(ws + (size_t)(132u << 20));
  u16*   wE1    = wBase;
  u16*   wE2    = wE1 + 524288;
  u16*   wE3    = wE2 + 262144;
  u16*   wD1    = wE3 + 262144;
  u16*   wD2    = wD1 + 262144;
  u16*   wD3    = wD2 + 262144;
  u16*   wMix   = wD3 + 524288;                        // 4 x 512 x 512

  cvt_all<<<512, 256, 0, stream>>>(enc_w1, enc_w2, enc_w3, dec_w1, dec_w2, dec_w3,
                                   mix_w, wBase);

  const int M = 65536;
  dim3 blk(512);
  const int g512  = 4 * 256;   // (N/128) * (M/256), 1-D swizzled
  const int g1024 = 8 * 256;

  // encoder
  gemm_bt<0, true ><<<g512, blk, 0, stream>>>(x,  wE1, enc_b1, zA, nullptr, nullptr, nullptr, M, 512, 1024);
  gemm_bt<0, false><<<g512, blk, 0, stream>>>(zA, wE2, enc_b2, zB, nullptr, nullptr, nullptr, M, 512, 512);
  gemm_bt<1, false><<<g512, blk, 0, stream>>>(zB, wE3, enc_b3, zA, nullptr, nullptr, nullptr, M, 512, 512);

  // latent layers
  u16* cur = zA;
  u16* nxt = zB;
  for (int l = 0; l < 4; ++l) {
    norm_mlp<<<2048, dim3(256), 0, stream>>>(cur, mlp1_w + l * 1024, mlp1_b + l * 64,
                                             mlp2_w + l * 4096, mlp2_b + l * 64,
                                             mlp3_w + l * 1024, scales, M);
    gemm_bt<2, false><<<g512, blk, 0, stream>>>(cur, wMix + (size_t)l * 262144, nullptr, nxt,
                                                cur, scales, gate_b + l * 16, M, 512, 512);
    u16* t = cur; cur = nxt; nxt = t;
  }

  // decoder
  gemm_bt<0, false><<<g512, blk, 0, stream>>>(cur, wD1, dec_b1, nxt, nullptr, nullptr, nullptr, M, 512, 512);
  { u16* t = cur; cur = nxt; nxt = t; }
  gemm_bt<0, false><<<g512, blk, 0, stream>>>(cur, wD2, dec_b2, nxt, nullptr, nullptr, nullptr, M, 512, 512);
  { u16* t = cur; cur = nxt; nxt = t; }
  gemm_bt<3, false><<<g1024, blk, 0, stream>>>(cur, wD3, dec_b3, d_out, nullptr, nullptr, nullptr, M, 1024, 512);
}

// Round 3
// 1517.408 us; speedup vs baseline: 3.2858x; 3.2858x over previous
//
#include <hip/hip_runtime.h>
#include <hip/hip_bf16.h>

typedef float f32x4 __attribute__((ext_vector_type(4)));
typedef __bf16 bf16x8 __attribute__((ext_vector_type(8)));
typedef unsigned short u16x8 __attribute__((ext_vector_type(8)));
typedef unsigned short u16;

__device__ __forceinline__ u16 f2bf(float f) {
  unsigned int u = __float_as_uint(f);
  u += 0x7FFFu + ((u >> 16) & 1u);          // RNE
  return (u16)(u >> 16);
}
__device__ __forceinline__ float bf2f(u16 s) {
  return __uint_as_float(((unsigned int)s) << 16);
}
__device__ __forceinline__ float gelu_f(float x) {
  return 0.5f * x * (1.0f + erff(x * 0.70710678118654752f)); // erf GELU
}
__device__ __forceinline__ void gload_lds16(const void* g, void* l) {
  __builtin_amdgcn_global_load_lds((const __attribute__((address_space(1))) void*)g,
                                   (__attribute__((address_space(3))) void*)l, 16, 0, 0);
}

// ---------------- merged weight conversion ----------------
// dst layout (contiguous u16): wE1(524288) wE2(262144) wE3(262144) wD1(262144)
//                              wD2(262144) wD3(524288) wMix(1048576)
__global__ void cvt_all(const float* __restrict__ e1, const float* __restrict__ e2,
                        const float* __restrict__ e3, const float* __restrict__ d1,
                        const float* __restrict__ d2, const float* __restrict__ d3,
                        const float* __restrict__ mx, u16* __restrict__ dst)
{
  int i = blockIdx.x * blockDim.x + threadIdx.x;
  int stride = gridDim.x * blockDim.x;
  for (; i < 3145728; i += stride) {
    float v;
    if (i < 524288)        v = e1[i];
    else if (i < 786432)   v = e2[i - 524288];
    else if (i < 1048576)  v = e3[i - 786432];
    else if (i < 1310720)  v = d1[i - 1048576];
    else if (i < 1572864)  v = d2[i - 1310720];
    else if (i < 2097152)  v = d3[i - 1572864];
    else {
      // mix_w [L,16,16,32,32] (l,bi,j,e,d) -> W[l][o=bi*32+e][k=j*32+d]
      int j = i - 2097152;
      int l = j >> 18, rem = j & 262143;
      int o = rem >> 9, k = rem & 511;
      int bi = o >> 5, e = o & 31, jj = k >> 5, dd = k & 31;
      v = mx[(((l * 16 + bi) * 16 + jj) * 32 + e) * 32 + dd];
    }
    dst[i] = f2bf(v);
  }
}

// ---------------- GEMM: C = A * W^T (+epilogue) ----------------
// EPI: 0 = bias+GELU -> bf16 ; 1 = bias -> bf16 ; 2 = latent combine -> bf16 ; 3 = bias -> f32
// BM=256, BN=128, BK=64, 512 threads (8 waves as 4x2), 1-D grid with XCD swizzle.
// launch_bounds(512,2): floor only — r2's (512,6) capped VGPR to 40 and spilled
// the accumulator to scratch (WRITE_SIZE 64MB -> 1.65GB, 4x slowdown).
template<int EPI, bool AF32>
__global__ __launch_bounds__(512, 2)
void gemm_bt(const void* __restrict__ Ap, const u16* __restrict__ Bw,
             const float* __restrict__ bias, void* __restrict__ Cp,
             const u16* __restrict__ zOld, const float* __restrict__ scales,
             const float* __restrict__ gateBias, int M, int N, int K)
{
  constexpr int BK = 64;
  __shared__ u16 At[256 * BK];
  __shared__ u16 Bt[128 * BK];
  const int tid = threadIdx.x;
  const int lane = tid & 63;
  const int wid = tid >> 6;

  // XCD-aware bijective swizzle: XCD c = bid&7 handles a contiguous panel range;
  // the nx blocks sharing an A-panel are adjacent within the XCD's sequence.
  const int nx = N >> 7;               // N-tiles (BN=128)
  const int ny = M >> 8;               // M-panels (BM=256), ny % 8 == 0
  const int d = blockIdx.x;
  const int xcd = d & 7;
  const int i = d >> 3;                // per-XCD sequence index
  const int by = xcd * (ny >> 3) + i / nx;
  const int bx = i - (i / nx) * nx;
  const int m0 = by << 8;
  const int n0 = bx << 7;

  const int wr = wid >> 1, wc = wid & 1;   // 4x2 wave grid, wave tile 64x64
  const int r16 = lane & 15;
  const int kg = (lane >> 4) << 3;         // k sub-offset 0,8,16,24
  const int sw = (r16 & 7) << 4;           // XOR swizzle for ds_read rows

  f32x4 acc[4][4] = {};

  for (int kt = 0; kt < K; kt += BK) {
    // ---- stage A tile [256 x 64] bf16, XOR-swizzled ----
    if constexpr (AF32) {
      const float* Af = (const float*)Ap;
      #pragma unroll
      for (int it = 0; it < 4; ++it) {
        int c = it * 512 + tid;            // 16B-dst chunk id, 2048 chunks
        int row = c >> 3;
        int cb = (c & 7) << 4;
        const float* src = Af + (size_t)(m0 + row) * K + kt + ((c & 7) << 3);
        float4 v0 = *(const float4*)src;
        float4 v1 = *(const float4*)(src + 4);
        u16x8 u;
        u[0] = f2bf(v0.x); u[1] = f2bf(v0.y); u[2] = f2bf(v0.z); u[3] = f2bf(v0.w);
        u[4] = f2bf(v1.x); u[5] = f2bf(v1.y); u[6] = f2bf(v1.z); u[7] = f2bf(v1.w);
        *(u16x8*)((char*)At + row * 128 + (cb ^ ((row & 7) << 4))) = u;
      }
    } else {
      const u16* Ab = (const u16*)Ap;
      #pragma unroll
      for (int it = 0; it < 4; ++it) {
        int c = ((it * 8 + wid) << 6) + lane;       // 2048 chunks
        int row = c >> 3;
        int cb = (c & 7) << 4;
        // rule 21: linear LDS dest + inverse-swizzled global source
        const char* g = (const char*)(Ab + (size_t)(m0 + row) * K + kt) + (cb ^ ((row & 7) << 4));
        char* l = (char*)At + ((it * 8 + wid) << 10);   // wave-uniform base
        gload_lds16(g, l);
      }
    }
    // ---- stage B tile [128 x 64] (weights) ----
    #pragma unroll
    for (int it = 0; it < 2; ++it) {
      int c = ((it * 8 + wid) << 6) + lane;         // 1024 chunks
      int row = c >> 3;
      int cb = (c & 7) << 4;
      const char* g = (const char*)(Bw + (size_t)(n0 + row) * K + kt) + (cb ^ ((row & 7) << 4));
      char* l = (char*)Bt + ((it * 8 + wid) << 10);
      gload_lds16(g, l);
    }
    __syncthreads();

    #pragma unroll
    for (int kk = 0; kk < BK; kk += 32) {
      bf16x8 av[4], bv[4];
      #pragma unroll
      for (int m = 0; m < 4; ++m) {
        int row = wr * 64 + m * 16 + r16;
        av[m] = *(const bf16x8*)((const char*)At + row * 128 + ((((kk + kg) << 1)) ^ sw));
      }
      #pragma unroll
      for (int n = 0; n < 4; ++n) {
        int row = wc * 64 + n * 16 + r16;
        bv[n] = *(const bf16x8*)((const char*)Bt + row * 128 + ((((kk + kg) << 1)) ^ sw));
      }
      #pragma unroll
      for (int m = 0; m < 4; ++m)
        #pragma unroll
        for (int n = 0; n < 4; ++n)
          acc[m][n] = __builtin_amdgcn_mfma_f32_16x16x32_bf16(av[m], bv[n], acc[m][n], 0, 0, 0);
    }
    __syncthreads();
  }

  // ---- epilogue ----  D layout: col = lane&15, row = (lane>>4)*4 + reg
  const int colBase = n0 + wc * 64 + r16;
  const int rowBase = m0 + wr * 64 + ((lane >> 4) << 2);
  #pragma unroll
  for (int n = 0; n < 4; ++n) {
    int col = colBase + n * 16;
    float bv_ = 0.f, gate = 0.f;
    if constexpr (EPI == 0 || EPI == 1 || EPI == 3) bv_ = bias[col];
    if constexpr (EPI == 2) gate = 1.f / (1.f + expf(-gateBias[col >> 5]));
    #pragma unroll
    for (int m = 0; m < 4; ++m) {
      #pragma unroll
      for (int r = 0; r < 4; ++r) {
        int row = rowBase + m * 16 + r;
        float v = acc[m][n][r];
        if constexpr (EPI == 0) {
          ((u16*)Cp)[(size_t)row * N + col] = f2bf(gelu_f(v + bv_));
        } else if constexpr (EPI == 1) {
          ((u16*)Cp)[(size_t)row * N + col] = f2bf(v + bv_);
        } else if constexpr (EPI == 2) {
          float sc = scales[(size_t)row * 16 + (col >> 5)];
          float zo = bf2f(zOld[(size_t)row * 512 + col]);
          ((u16*)Cp)[(size_t)row * N + col] = f2bf(zo * (1.f + sc) + gate * v);
        } else {
          ((float*)Cp)[(size_t)row * N + col] = v + bv_;
        }
      }
    }
  }
}

// ---------------- per-row bundle-norm MLP -> scales ----------------
__global__ __launch_bounds__(256)
void norm_mlp(const u16* __restrict__ z,
              const float* __restrict__ w1, const float* __restrict__ b1,
              const float* __restrict__ w2, const float* __restrict__ b2,
              const float* __restrict__ w3, float* __restrict__ scales, int Mrows)
{
  const int lane = threadIdx.x & 63;
  const int wv = threadIdx.x >> 6;
  for (int row = blockIdx.x * 4 + wv; row < Mrows; row += gridDim.x * 4) {
    u16x8 zv = *(const u16x8*)(z + (size_t)row * 512 + lane * 8);
    float ss = 0.f;
    #pragma unroll
    for (int j = 0; j < 8; ++j) { float f = bf2f(zv[j]); ss += f * f; }
    ss += __shfl_xor(ss, 1);
    ss += __shfl_xor(ss, 2);                 // 4-lane group = one 32-elem bundle
    float nrm = sqrtf(ss) + 1e-8f;
    float h1 = b1[lane];
    #pragma unroll
    for (int i = 0; i < 16; ++i) h1 += __shfl(nrm, i * 4) * w1[lane * 16 + i];
    h1 = gelu_f(h1);
    float h2 = b2[lane];
    #pragma unroll
    for (int k = 0; k < 64; ++k) h2 += __shfl(h1, k) * w2[lane * 64 + k];
    h2 = gelu_f(h2);
    float s = 0.f;
    const int i16 = lane & 15;
    #pragma unroll
    for (int k = 0; k < 64; ++k) s += __shfl(h2, k) * w3[i16 * 64 + k];
    if (lane < 16) {
      s = (s > 20.f) ? s : log1pf(expf(s));  // softplus
      scales[(size_t)row * 16 + lane] = s;
    }
  }
}

// ---------------- launch ----------------
extern "C" void kernel_launch(void* const* d_in, const int* in_sizes, int n_in,
                              void* d_out, int out_size, void* d_ws, size_t ws_size,
                              hipStream_t stream)
{
  (void)in_sizes; (void)n_in; (void)out_size; (void)ws_size;
  const float* x      = (const float*)d_in[0];
  const float* enc_w1 = (const float*)d_in[1];
  const float* enc_b1 = (const float*)d_in[2];
  const float* enc_w2 = (const float*)d_in[3];
  const float* enc_b2 = (const float*)d_in[4];
  const float* enc_w3 = (const float*)d_in[5];
  const float* enc_b3 = (const float*)d_in[6];
  const float* mlp1_w = (const float*)d_in[7];
  const float* mlp1_b = (const float*)d_in[8];
  const float* mlp2_w = (const float*)d_in[9];
  const float* mlp2_b = (const float*)d_in[10];
  const float* mlp3_w = (const float*)d_in[11];
  const float* mix_w  = (const float*)d_in[12];
  const float* gate_b = (const float*)d_in[13];
  const float* dec_w1 = (const float*)d_in[14];
  const float* dec_b1 = (const float*)d_in[15];
  const float* dec_w2 = (const float*)d_in[16];
  const float* dec_b2 = (const float*)d_in[17];
  const float* dec_w3 = (const float*)d_in[18];
  const float* dec_b3 = (const float*)d_in[19];

  char* ws = (char*)d_ws;
  u16*   zA     = (u16*)ws;                            // 64 MB
  u16*   zB     = (u16*)(ws + (size_t)(64u << 20));    // 64 MB
  float* scales = (float*)(ws + (size_t)(128u << 20)); // 4 MB
  u16*   wBase  = (u16*)(ws + (size_t)(132u << 20));
  u16*   wE1    = wBase;
  u16*   wE2    = wE1 + 524288;
  u16*   wE3    = wE2 + 262144;
  u16*   wD1    = wE3 + 262144;
  u16*   wD2    = wD1 + 262144;
  u16*   wD3    = wD2 + 262144;
  u16*   wMix   = wD3 + 524288;                        // 4 x 512 x 512

  cvt_all<<<512, 256, 0, stream>>>(enc_w1, enc_w2, enc_w3, dec_w1, dec_w2, dec_w3,
                                   mix_w, wBase);

  const int M = 65536;
  dim3 blk(512);
  const int g512  = 4 * 256;   // (N/128) * (M/256), 1-D swizzled
  const int g1024 = 8 * 256;

  // encoder
  gemm_bt<0, true ><<<g512, blk, 0, stream>>>(x,  wE1, enc_b1, zA, nullptr, nullptr, nullptr, M, 512, 1024);
  gemm_bt<0, false><<<g512, blk, 0, stream>>>(zA, wE2, enc_b2, zB, nullptr, nullptr, nullptr, M, 512, 512);
  gemm_bt<1, false><<<g512, blk, 0, stream>>>(zB, wE3, enc_b3, zA, nullptr, nullptr, nullptr, M, 512, 512);

  // latent layers
  u16* cur = zA;
  u16* nxt = zB;
  for (int l = 0; l < 4; ++l) {
    norm_mlp<<<2048, dim3(256), 0, stream>>>(cur, mlp1_w + l * 1024, mlp1_b + l * 64,
                                             mlp2_w + l * 4096, mlp2_b + l * 64,
                                             mlp3_w + l * 1024, scales, M);
    gemm_bt<2, false><<<g512, blk, 0, stream>>>(cur, wMix + (size_t)l * 262144, nullptr, nxt,
                                                cur, scales, gate_b + l * 16, M, 512, 512);
    u16* t = cur; cur = nxt; nxt = t;
  }

  // decoder
  gemm_bt<0, false><<<g512, blk, 0, stream>>>(cur, wD1, dec_b1, nxt, nullptr, nullptr, nullptr, M, 512, 512);
  { u16* t = cur; cur = nxt; nxt = t; }
  gemm_bt<0, false><<<g512, blk, 0, stream>>>(cur, wD2, dec_b2, nxt, nullptr, nullptr, nullptr, M, 512, 512);
  { u16* t = cur; cur = nxt; nxt = t; }
  gemm_bt<3, false><<<g1024, blk, 0, stream>>>(cur, wD3, dec_b3, d_out, nullptr, nullptr, nullptr, M, 1024, 512);
}